// Round 7
// baseline (388.032 us; speedup 1.0000x reference)
//
#include <hip/hip_runtime.h>
#include <cstdint>

#define BB 16
#define NN 25200
#define NCLS 80
#define ROW 85
#define MAXDET 300
#define HBINS 2048
#define CAP2 512
#define TGT 448
#define CONF_T 0.25f
#define IOU_T 0.45f

// ---------------- workspace layout (bytes) ----------------
// hist u32[BB][HBINS] @ 0        (131072)   zeroed by memset each launch
// cnt  i32[BB]        @ 131072   (64)
// keys u64[BB][CAP2]  @ 131136   (65536)
// scr  f32[BB*NN]     @ 196672   (1612800)
static const size_t OFF_CNT  = 131072;
static const size_t OFF_KEYS = 131136;
static const size_t OFF_SCR  = 196672;

// Quad-per-row score + per-image global hist (only ~4% lanes atomic).
__global__ __launch_bounds__(256) void k_pre(const float* __restrict__ pred,
                                             float* __restrict__ scoreArr,
                                             unsigned* __restrict__ hist) {
    int tid = threadIdx.x;
    int t = tid & 3;
    int row = blockIdx.x * 64 + (tid >> 2);
    const float* rp = pred + (size_t)row * ROW;
    int start = (t == 0) ? 0 : (1 + 21 * t);   // 0,22,43,64
    int cnt   = (t == 0) ? 22 : 21;
    float obj = rp[4];
    float best = -1.0f; int bc = 1 << 20;
#pragma unroll
    for (int k = 0; k < 22; ++k) {
        if (k < cnt) {
            int col = start + k;
            if (col >= 5) {
                float v = __fmul_rn(rp[col], obj);
                if (v > best) { best = v; bc = col; }
            }
        }
    }
#pragma unroll
    for (int d = 1; d <= 2; d <<= 1) {
        float ob = __shfl_xor(best, d);
        int   oc = __shfl_xor(bc, d);
        if (ob > best || (ob == best && oc < bc)) { best = ob; bc = oc; }
    }
    if (t == 0) {
        bool valid = (obj > CONF_T) && (best > CONF_T);
        scoreArr[row] = valid ? best : -1.0f;
        if (valid) {
            unsigned key = (__float_as_uint(best) - 0x3E800000u) >> 13;
            if (key > HBINS - 1) key = HBINS - 1;
            atomicAdd(&hist[(row / NN) * HBINS + key], 1u);
        }
    }
}

// 128 blocks (8/image): redundant threshold from hist + ballot-compact slice.
__global__ __launch_bounds__(256) void k_sel(const float* __restrict__ scoreArr,
                                             const unsigned* __restrict__ histG,
                                             int* __restrict__ cntG,
                                             unsigned long long* __restrict__ keysG) {
    __shared__ unsigned h[HBINS];
    __shared__ unsigned csum[257];
    __shared__ int s_thr;
    int b = blockIdx.x >> 3, slice = blockIdx.x & 7;
    int tid = threadIdx.x, lane = tid & 63;

    for (int k = tid; k < HBINS; k += 256) h[k] = histG[b * HBINS + k];
    if (tid == 0) s_thr = 0;
    __syncthreads();

    // suffix scan -> threshold bin (verified r2-r6 logic, 256 threads)
    unsigned cs = 0;
#pragma unroll
    for (int t = 0; t < 8; ++t) cs += h[tid * 8 + t];
    csum[tid] = cs;
    __syncthreads();
    for (int off = 1; off < 256; off <<= 1) {
        unsigned v = csum[tid];
        unsigned add = (tid + off < 256) ? csum[tid + off] : 0u;
        __syncthreads();
        csum[tid] = v + add;
        __syncthreads();
    }
    {
        unsigned Sc = csum[tid];
        unsigned Sn = (tid < 255) ? csum[tid + 1] : 0u;
        if (Sc >= TGT && (tid == 255 || Sn < TGT)) {
            unsigned cum = Sn;
            int t = tid * 8;
            for (int k = tid * 8 + 7; k >= tid * 8; --k) {
                cum += h[k];
                if (cum >= TGT) { t = k; break; }
            }
            s_thr = t;
        }
    }
    __syncthreads();
    unsigned thr = (unsigned)s_thr;

    // ballot-aggregated compact of this block's 3150-score slice (13 fixed rounds)
    int base_n = slice * (NN / 8);
    for (int r = 0; r < 13; ++r) {
        int n = base_n + r * 256 + tid;
        bool in = (r * 256 + tid) < (NN / 8);
        float s = in ? scoreArr[(size_t)b * NN + n] : -1.0f;
        bool win = false;
        if (s > 0.0f) {
            unsigned key = (__float_as_uint(s) - 0x3E800000u) >> 13;
            if (key > HBINS - 1) key = HBINS - 1;
            win = (key >= thr);
        }
        unsigned long long m = __ballot(win);
        if (m) {
            int lead = __ffsll((long long)m) - 1;
            int basep = 0;
            if (lane == lead) basep = atomicAdd(&cntG[b], __popcll(m));
            basep = __shfl(basep, lead);
            if (win) {
                int pos = basep + __popcll(m & ((1ULL << lane) - 1ULL));
                if (pos < CAP2)
                    keysG[b * CAP2 + pos] = ((unsigned long long)__float_as_uint(s) << 32)
                                          | (unsigned long long)(0xFFFFFFFFu - (unsigned)n);
            }
        }
    }
}

// 16 blocks x 1024: sort -> recompute -> in-LDS mask/maskT -> fixpoint resolve
// -> rank-scatter outputs. All logic bitwise-reused from validated rounds.
__global__ __launch_bounds__(1024) void k_fin(const float* __restrict__ pred,
                                              const float* __restrict__ logits,
                                              const unsigned long long* __restrict__ keysG,
                                              const int* __restrict__ ccnt,
                                              float* __restrict__ out) {
    __shared__ unsigned long long keys[CAP2];        // 4KB
    __shared__ float4 cbox[CAP2];                    // 8KB
    __shared__ float4 rawb[CAP2];                    // 8KB
    __shared__ unsigned ccls[CAP2];                  // 2KB
    __shared__ unsigned long long maskS[CAP2 * 8];   // 32KB
    __shared__ unsigned long long maskT[8 * 64];     // 4KB
    __shared__ unsigned rowsrc_s[MAXDET];
    __shared__ unsigned kidx[64];
    __shared__ unsigned long long keepm_s[8];
    __shared__ int s_kept;

    int b = blockIdx.x, tid = threadIdx.x;
    int c = min(ccnt[b], CAP2);

    if (tid < CAP2) keys[tid] = (tid < c) ? keysG[b * CAP2 + tid] : 0ULL;
    __syncthreads();

    // bitonic sort 512 u64 desc == (score desc, idx asc) — exact reference order
    for (int k = 2; k <= CAP2; k <<= 1) {
        for (int j = k >> 1; j > 0; j >>= 1) {
            if (tid < CAP2) {
                int i = tid, ixj = i ^ j;
                if (ixj > i) {
                    unsigned long long k1 = keys[i], k2 = keys[ixj];
                    bool sw = ((i & k) == 0) ? (k1 < k2) : (k1 > k2);
                    if (sw) { keys[i] = k2; keys[ixj] = k1; }
                }
            }
            __syncthreads();
        }
    }

    // recompute argmax/box for sorted candidates (bitwise = reference)
    if (tid < CAP2) {
        int p = tid;
        if (p < c) {
            int n = (int)(0xFFFFFFFFu - (unsigned)keys[p]);
            const float* rp = pred + ((size_t)b * NN + n) * ROW;
            float cx = rp[0], cy = rp[1], w = rp[2], h = rp[3], obj = rp[4];
            float best = __fmul_rn(rp[5], obj);
            int bj = 0;
#pragma unroll 8
            for (int cc = 1; cc < NCLS; ++cc) {
                float v = __fmul_rn(rp[5 + cc], obj);
                if (v > best) { best = v; bj = cc; }
            }
            float hw = __fmul_rn(w, 0.5f), hh = __fmul_rn(h, 0.5f);
            float4 bb = make_float4(__fsub_rn(cx, hw), __fsub_rn(cy, hh),
                                    __fadd_rn(cx, hw), __fadd_rn(cy, hh));
            rawb[p] = bb;
            float off = __fmul_rn((float)bj, 4096.0f);
            cbox[p] = make_float4(__fadd_rn(bb.x, off), __fadd_rn(bb.y, off),
                                  __fadd_rn(bb.z, off), __fadd_rn(bb.w, off));
            ccls[p] = (unsigned)bj;
        } else {
            rawb[p] = make_float4(0.f, 0.f, 0.f, 0.f);
            cbox[p] = make_float4(0.f, 0.f, 0.f, 0.f);
            ccls[p] = 0u;
        }
    }
    __syncthreads();

    // forward-only pairwise suppression bits (j > i), 4096 tasks / 1024 threads
    for (int task = tid; task < CAP2 * 8; task += 1024) {
        int i = task & (CAP2 - 1);
        int w = task >> 9;
        int jbase = w << 6;
        unsigned long long m = 0ULL;
        if (i < c && i < jbase + 63) {
            float4 ci = cbox[i];
            float a1 = __fmul_rn(__fsub_rn(ci.z, ci.x), __fsub_rn(ci.w, ci.y));
#pragma unroll 4
            for (int jj = 0; jj < 64; ++jj) {
                int j = jbase + jj;
                float4 cj = cbox[j];
                float ltx = fmaxf(ci.x, cj.x), lty = fmaxf(ci.y, cj.y);
                float rbx = fminf(ci.z, cj.z), rby = fminf(ci.w, cj.w);
                float ww = fmaxf(__fsub_rn(rbx, ltx), 0.0f);
                float hh = fmaxf(__fsub_rn(rby, lty), 0.0f);
                float inter = __fmul_rn(ww, hh);
                if (j > i && inter > 0.0f) {
                    float a2 = __fmul_rn(__fsub_rn(cj.z, cj.x), __fsub_rn(cj.w, cj.y));
                    float denom = __fadd_rn(__fsub_rn(__fadd_rn(a1, a2), inter), 1e-9f);
                    if (inter / denom > IOU_T) m |= (1ULL << jj);
                }
            }
        }
        maskS[i * 8 + w] = m;
    }
    // transposed diagonal blocks: column l = earlier same-word suppressors of l.
    // IoU operand order identical to row-major (a1 from row ii, a2 from col l).
    if (tid < CAP2) {
        int l = tid & 63, w = tid >> 6;
        int jbase = w << 6, p = jbase + l;
        unsigned long long m = 0ULL;
        if (p < c) {
            float4 cl = cbox[p];
            float a2 = __fmul_rn(__fsub_rn(cl.z, cl.x), __fsub_rn(cl.w, cl.y));
            for (int ii = 0; ii < 64; ++ii) {
                float4 ci = cbox[jbase + ii];
                float ltx = fmaxf(ci.x, cl.x), lty = fmaxf(ci.y, cl.y);
                float rbx = fminf(ci.z, cl.z), rby = fminf(ci.w, cl.w);
                float ww = fmaxf(__fsub_rn(rbx, ltx), 0.0f);
                float hh = fmaxf(__fsub_rn(rby, lty), 0.0f);
                float inter = __fmul_rn(ww, hh);
                if (ii < l && inter > 0.0f) {
                    float a1 = __fmul_rn(__fsub_rn(ci.z, ci.x), __fsub_rn(ci.w, ci.y));
                    float denom = __fadd_rn(__fsub_rn(__fadd_rn(a1, a2), inter), 1e-9f);
                    if (inter / denom > IOU_T) m |= (1ULL << ii);
                }
            }
        }
        maskT[w * 64 + l] = m;
    }
    __syncthreads();

    // ballot-fixpoint greedy resolve on wave 0 (r6-validated, masks now in LDS)
    if (tid < 64) {
        int lane = tid;
        unsigned long long remq = 0ULL;  // lane q<8 owns rem word q
        int kept = 0;
        for (int w = 0; w < 8; ++w) {
            int base = w << 6;
            unsigned long long tw = __shfl(remq, w);
            bool pre = ((tw >> lane) & 1ULL) != 0ULL;
            bool validl = (base + lane) < c;
            unsigned long long Cl = maskT[w * 64 + lane];
            unsigned long long initK = __ballot(validl && !pre);
            unsigned long long K = initK;
            for (int it = 0; it < 64; ++it) {
                bool sup = (Cl & K & ((1ULL << lane) - 1ULL)) != 0ULL;
                unsigned long long K2 = initK & __ballot(!sup);
                if (K2 == K) break;
                K = K2;
            }
            int limit = MAXDET - kept;
            int nk = __popcll(K);
            if (nk > limit) {
                if (limit <= 0) K = 0ULL;
                else {
                    int pref = __popcll(K & ((2ULL << lane) - 1ULL));
                    bool el = ((K >> lane) & 1ULL) && (pref <= limit);
                    K = __ballot(el);
                }
            }
            kept += __popcll(K);
            if (lane == 0) keepm_s[w] = K;
            if (K != 0ULL && w < 7) {
                if ((K >> lane) & 1ULL) {
                    int r = __popcll(K & ((1ULL << lane) - 1ULL));
                    kidx[r] = (unsigned)lane;
                }
                __builtin_amdgcn_s_waitcnt(0);
                int nkk = __popcll(K);
                int q = lane & 7, slot = lane >> 3;
                unsigned long long acc = 0ULL;
                for (int t = slot; t < nkk; t += 8)
                    acc |= maskS[(base + (int)kidx[t]) * 8 + q];
                acc |= __shfl_xor(acc, 8);
                acc |= __shfl_xor(acc, 16);
                acc |= __shfl_xor(acc, 32);
                if (slot == 0) remq |= acc;
            }
        }
        if (lane == 0) s_kept = kept;
    }
    __syncthreads();
    int kept = s_kept;

    float* dets = out;
    float* lg   = out + (size_t)BB * MAXDET * 6;
    float* kpo  = lg  + (size_t)BB * MAXDET * NCLS;

    // rank-scatter kept rows directly to dets; record source indices
    if (tid < CAP2) {
        int p = tid;
        if (p < c) {
            int w = p >> 6, bitp = p & 63;
            unsigned long long kw = keepm_s[w];
            if ((kw >> bitp) & 1ULL) {
                int rank = __popcll(kw & ((1ULL << bitp) - 1ULL));
                for (int q = 0; q < w; ++q) rank += __popcll(keepm_s[q]);
                if (rank < MAXDET) {
                    float4 bb = rawb[p];
                    float* dr = dets + ((size_t)b * MAXDET + rank) * 6;
                    dr[0] = bb.x; dr[1] = bb.y; dr[2] = bb.z; dr[3] = bb.w;
                    dr[4] = __uint_as_float((unsigned)(keys[p] >> 32));
                    dr[5] = (float)ccls[p];
                    rowsrc_s[rank] = 0xFFFFFFFFu - (unsigned)keys[p];
                }
            }
        }
    }
    for (int i = tid; i < MAXDET; i += 1024) {
        if (i >= kept) {
            float* dr = dets + ((size_t)b * MAXDET + i) * 6;
#pragma unroll
            for (int q = 0; q < 6; ++q) dr[q] = 0.0f;
        }
        kpo[b * MAXDET + i] = (i < kept) ? 1.0f : 0.0f;
    }
    __syncthreads();
    for (int i = tid; i < MAXDET * NCLS; i += 1024) {
        int t = i / NCLS, col = i - t * NCLS;
        float v = 0.0f;
        if (t < kept) v = logits[((size_t)b * NN + rowsrc_s[t]) * NCLS + col];
        lg[(size_t)b * MAXDET * NCLS + i] = v;
    }
}

extern "C" void kernel_launch(void* const* d_in, const int* in_sizes, int n_in,
                              void* d_out, int out_size, void* d_ws, size_t ws_size,
                              hipStream_t stream) {
    const float* pred   = (const float*)d_in[0];
    const float* logits = (const float*)d_in[1];
    float* out = (float*)d_out;
    char* ws = (char*)d_ws;

    unsigned* hist             = (unsigned*)ws;
    int* cnt                   = (int*)(ws + OFF_CNT);
    unsigned long long* keysG  = (unsigned long long*)(ws + OFF_KEYS);
    float* scr                 = (float*)(ws + OFF_SCR);

    hipMemsetAsync(ws, 0, OFF_KEYS, stream);  // hist + cnt (131136 B)

    k_pre<<<6300, 256, 0, stream>>>(pred, scr, hist);   // 403200/64 exact
    k_sel<<<BB * 8, 256, 0, stream>>>(scr, hist, cnt, keysG);
    k_fin<<<BB, 1024, 0, stream>>>(pred, logits, keysG, cnt, out);
}